// Round 7
// baseline (122.991 us; speedup 1.0000x reference)
//
#include <hip/hip_runtime.h>

// YOLOv1 head post-process — R7: R6 split architecture with the writer-underrun
// bug fixed (kernel C ran 512 threads against a 980-thread `if` body — rows
// 1024..1959 of every batch never written -> absmax 448 = all-zeros tail).
// Kernel C now runs 1024 threads. Everything else identical to R6:
//   A) prep (1024 blocks x 256): softmax+decode+adjacency -> ws
//   B) nms  (5120 blocks x 256): one wave per (batch,class), 20480 independent
//      wave-problems, no __syncthreads at all -> keep masks in ws
//   C) write(1024 blocks x 1024): streaming composer, coalesced float2/float4
// Falls back to the R5 monolithic kernel (known-passing, 46us) if ws too small.
// Equivalence notes (carried, R1-R5 all passed):
//  * score < SCORE_T boxes only suppress even-lower-sorted boxes (all zeroed
//    by the final score filter) -> NMS over score>=SCORE_T candidates exact.
//  * candidate => conf*maxprob >= SCORE_T in float (monotone rounding) ->
//    union-filtered adjacency rows cover every box the NMS can touch.
//  * rank tie-break = box index ascending = jnp stable argsort(-scores).
//  * K>64 per class (prob ~0) falls back to ballot-greedy (exact).

namespace {
constexpr int kS    = 7;
constexpr int kC    = 20;
constexpr int kFeat = 30;             // C + 5*BBOX
constexpr int kN    = 98;             // S*S*2 boxes
constexpr int kRows = kN * kC;        // 1960
constexpr int kOutF = kRows * 6;      // 11760 floats per batch
constexpr float kIouT   = 0.5f;
constexpr float kScoreT = 0.05f;
}

__device__ __forceinline__ float iou_f(float ax1, float ay1, float ax2, float ay2,
                                       float bx1, float by1, float bx2, float by2) {
#pragma clang fp contract(off)
    float aa = fmaxf(ax2 - ax1, 0.f) * fmaxf(ay2 - ay1, 0.f);
    float ab = fmaxf(bx2 - bx1, 0.f) * fmaxf(by2 - by1, 0.f);
    float ix1 = fmaxf(ax1, bx1);
    float iy1 = fmaxf(ay1, by1);
    float ix2 = fminf(ax2, bx2);
    float iy2 = fminf(ay2, by2);
    float inter = fmaxf(ix2 - ix1, 0.f) * fmaxf(iy2 - iy1, 0.f);
    float uni = aa + ab - inter;
    return inter / fmaxf(uni, 1e-9f);
}

__device__ __forceinline__ unsigned long long shfl64(unsigned long long v, int src) {
    unsigned lo = (unsigned)__shfl((int)(unsigned)(v & 0xffffffffull), src);
    unsigned hi = (unsigned)__shfl((int)(unsigned)(v >> 32), src);
    return ((unsigned long long)hi << 32) | lo;
}

// ---------------- Kernel A: preprocess (per batch) ----------------
__global__ __launch_bounds__(256) void yolo_prep_kernel(
        const float* __restrict__ x,
        float* __restrict__ scT,                 // [B][20][98]
        float* __restrict__ scN,                 // [B][98][20]
        float* __restrict__ bxs,                 // [B][98][4]
        unsigned* __restrict__ adjLo,            // [B][98] u64 as 2xu32
        unsigned* __restrict__ adjHi) {          // [B][98] u64 as 2xu32
    __shared__ float xs[kS * kS * kFeat];
    __shared__ float maxp[kS * kS];
    __shared__ __align__(16) float bxsh[kN * 4];

    const int b   = blockIdx.x;
    const int tid = threadIdx.x;
    const float* xb = x + (size_t)b * (kS * kS * kFeat);
    for (int e = tid; e < (kS * kS * kFeat) / 2; e += 256)
        reinterpret_cast<float2*>(xs)[e] = reinterpret_cast<const float2*>(xb)[e];
    __syncthreads();

    if (tid < kS * kS) {
#pragma clang fp contract(off)
        const int cell = tid;
        const float* p = &xs[cell * kFeat];
        float mx = p[0];
        for (int c = 1; c < kC; ++c) mx = fmaxf(mx, p[c]);
        float e[kC];
        float sum = 0.f;
        for (int c = 0; c < kC; ++c) { e[c] = expf(p[c] - mx); sum += e[c]; }
        const float conf0 = p[28], conf1 = p[29];
        float* sTb = scT + (size_t)b * kRows;
        float* sNb = scN + (size_t)b * kRows;
        for (int c = 0; c < kC; ++c) {
            float pr = e[c] / sum;
            float sA = pr * conf0;
            float sB = pr * conf1;
            sTb[c * kN + 2 * cell]     = sA;
            sTb[c * kN + 2 * cell + 1] = sB;
            sNb[(2 * cell) * kC + c]     = sA;
            sNb[(2 * cell + 1) * kC + c] = sB;
        }
        maxp[cell] = 1.0f / sum;    // exp(0)=1 is the exact max of e[]
    } else if (tid >= 64 && tid < 64 + kN) {
#pragma clang fp contract(off)
        const int n = tid - 64;
        const int cell = n >> 1, k = n & 1;
        const int gi = cell / kS, gj = cell % kS;   // gy=gi, gx=gj
        const float* p = &xs[cell * kFeat + kC + 4 * k];
        float cx = (p[0] + (float)gj) / 7.0f;
        float cy = (p[1] + (float)gi) / 7.0f;
        float w = p[2], h = p[3];
        float4 bb;
        bb.x = fminf(fmaxf(cx - w * 0.5f, 0.f), 1.f) * 448.f;
        bb.y = fminf(fmaxf(cy - h * 0.5f, 0.f), 1.f) * 448.f;
        bb.z = fminf(fmaxf(cx + w * 0.5f, 0.f), 1.f) * 448.f;
        bb.w = fminf(fmaxf(cy + h * 0.5f, 0.f), 1.f) * 448.f;
        *reinterpret_cast<float4*>(&bxsh[n * 4]) = bb;
        reinterpret_cast<float4*>(bxs)[(size_t)b * kN + n] = bb;
    }
    __syncthreads();

    // adjacency rows, only for union-candidate boxes (conf*maxp >= T)
    for (int it = tid; it < 4 * kN; it += 256) {
        const int i = it % kN;
        const int w = it / kN;
        const int cell = i >> 1, k = i & 1;
        const float conf = xs[cell * kFeat + 28 + k];
        if (conf * maxp[cell] >= kScoreT) {
            const float ax1 = bxsh[i * 4 + 0], ay1 = bxsh[i * 4 + 1];
            const float ax2 = bxsh[i * 4 + 2], ay2 = bxsh[i * 4 + 3];
            unsigned m = 0;
            const int j0 = 32 * w;
            const int j1 = (j0 + 32 < kN) ? (j0 + 32) : kN;
            for (int j = j0; j < j1; ++j) {
                float v = iou_f(ax1, ay1, ax2, ay2,
                                bxsh[j * 4 + 0], bxsh[j * 4 + 1],
                                bxsh[j * 4 + 2], bxsh[j * 4 + 3]);
                if (v > kIouT) m |= (1u << (j - j0));
            }
            if (w < 2) adjLo[((size_t)b * kN + i) * 2 + w] = m;
            else       adjHi[((size_t)b * kN + i) * 2 + (w - 2)] = m;
        }
    }
}

// ---------------- Kernel B: NMS, one wave per (batch, class) ----------------
__global__ __launch_bounds__(256) void yolo_nms_kernel(
        const float* __restrict__ scT,
        const float* __restrict__ bxs,
        const unsigned long long* __restrict__ adjLo,
        const unsigned long long* __restrict__ adjHi,
        unsigned* __restrict__ km) {             // [B][20][4]
    __shared__ float cscore[4][kN];
    __shared__ unsigned short cidx[4][kN];
    __shared__ unsigned short rnk[4][64];
    __shared__ unsigned short rid[4][64];

    const int wv = threadIdx.x >> 6;
    const int lane = threadIdx.x & 63;
    const int gw = blockIdx.x * 4 + wv;
    const int b = gw / kC;
    const int c = gw % kC;

    const float* sc = scT + (size_t)b * kRows + c * kN;
    float s0 = sc[lane];
    bool c0 = (s0 >= kScoreT);
    float s1 = 0.f;
    bool c1 = false;
    if (lane < kN - 64) {
        s1 = sc[64 + lane];
        c1 = (s1 >= kScoreT);
    }
    const unsigned long long m0 = __ballot(c0);
    const unsigned long long m1 = __ballot(c1);
    const int K0 = __popcll(m0);
    const int K  = K0 + __popcll(m1);
    const unsigned long long lt = (1ull << lane) - 1ull;
    int p0 = 0, p1 = 0;
    if (c0) {
        p0 = __popcll(m0 & lt);
        cscore[wv][p0] = s0;
        cidx[wv][p0] = (unsigned short)lane;
    }
    if (c1) {
        p1 = K0 + __popcll(m1 & lt);
        cscore[wv][p1] = s1;
        cidx[wv][p1] = (unsigned short)(lane + 64);
    }
    __builtin_amdgcn_wave_barrier();

    unsigned long long kb0 = 0, kb1 = 0;   // keep ballots (box space)
    if (K <= 64) {
        const bool act = (lane < K);
        const float sp = act ? cscore[wv][lane] : 0.f;
        int rp = 0;
        for (int q = 0; q < K; ++q) {
            float sq = cscore[wv][q];                 // broadcast read
            rp += ((sq > sp) || ((sq == sp) && (q < lane))) ? 1 : 0;
        }
        if (act) {
            rnk[wv][lane] = (unsigned short)rp;
            rid[wv][rp] = cidx[wv][lane];
        }
        __builtin_amdgcn_wave_barrier();
        const int myb = act ? (int)rid[wv][lane] : 0;
        const unsigned long long rLo = act ? adjLo[(size_t)b * kN + myb] : 0ull;
        const unsigned long long rHi = act ? adjHi[(size_t)b * kN + myb] : 0ull;
        unsigned long long supLo = 0, supHi = 0, keepM = 0;
        for (int r = 0; r < K; ++r) {
            const int bi = __shfl(myb, r);            // indep of sup chain
            const unsigned long long qLo = shfl64(rLo, r);
            const unsigned long long qHi = shfl64(rHi, r);
            const unsigned long long word = (bi & 64) ? supHi : supLo;
            const unsigned long long bit = (word >> (bi & 63)) & 1ull;
            const unsigned long long take = bit - 1ull; // ~0 if still alive
            keepM |= (1ull << r) & take;
            supLo |= qLo & take;
            supHi |= qHi & take;
        }
        const bool k0 = c0 && ((keepM >> rnk[wv][p0]) & 1ull);
        const bool k1 = c1 && ((keepM >> rnk[wv][p1]) & 1ull);
        kb0 = __ballot(k0);
        kb1 = __ballot(k1);
    } else {
        // fallback (K>64, probability ~0): ballot-greedy over candidates
        const float4* bx4 = reinterpret_cast<const float4*>(bxs) + (size_t)b * kN;
        bool al0 = c0, al1 = c1;
        bool k0 = false, k1 = false;
        const float4 nb0 = bx4[lane];
        float4 nb1 = make_float4(0.f, 0.f, 0.f, 0.f);
        if (lane < kN - 64) nb1 = bx4[lane + 64];
        for (;;) {
            float bs; int bp;
            if (al0 && (!al1 || s0 >= s1)) { bs = s0; bp = p0; }
            else if (al1)                  { bs = s1; bp = p1; }
            else                           { bs = -1e30f; bp = 1 << 20; }
            for (int off = 32; off; off >>= 1) {
                float os = __shfl_xor(bs, off);
                int   op = __shfl_xor(bp, off);
                if (os > bs || (os == bs && op < bp)) { bs = os; bp = op; }
            }
            if (bp >= (1 << 20)) break;
            const int bi = cidx[wv][bp];              // wave-uniform
            const float4 kbx = bx4[bi];
            if (bp == p0 && al0) { k0 = true; al0 = false; }
            if (bp == p1 && al1) { k1 = true; al1 = false; }
            if (al0 && iou_f(kbx.x, kbx.y, kbx.z, kbx.w,
                             nb0.x, nb0.y, nb0.z, nb0.w) > kIouT) al0 = false;
            if (al1 && iou_f(kbx.x, kbx.y, kbx.z, kbx.w,
                             nb1.x, nb1.y, nb1.z, nb1.w) > kIouT) al1 = false;
        }
        kb0 = __ballot(k0);
        kb1 = __ballot(k1);
    }
    if (lane == 0) {
        uint4 v;
        v.x = (unsigned)kb0;
        v.y = (unsigned)(kb0 >> 32);
        v.z = (unsigned)kb1;
        v.w = (unsigned)(kb1 >> 32);
        *reinterpret_cast<uint4*>(km + (size_t)(b * kC + c) * 4) = v;
    }
}

// ---------------- Kernel C: streaming writer (per batch) ----------------
__global__ __launch_bounds__(1024) void yolo_write_kernel(
        const float* __restrict__ scN,
        const float* __restrict__ bxs,
        const unsigned* __restrict__ km,
        float* __restrict__ out) {
    __shared__ unsigned kmsh[kC * 4];
    __shared__ __align__(16) float bxsh[kN * 4];

    const int b   = blockIdx.x;
    const int tid = threadIdx.x;
    if (tid < kC * 4) kmsh[tid] = km[(size_t)b * kC * 4 + tid];
    else if (tid >= 128 && tid < 128 + kN)
        reinterpret_cast<float4*>(bxsh)[tid - 128] =
            reinterpret_cast<const float4*>(bxs)[(size_t)b * kN + (tid - 128)];
    __syncthreads();

    if (tid < kRows / 2) {                    // 980 workers, block = 1024 (R6 bug fix)
        const int j = tid;
        const int n = j / 10;                 // rows 2j,2j+1 share n
        const int c0i = 2 * (j % 10);
        const float2 s2 = *reinterpret_cast<const float2*>(
            scN + (size_t)b * kRows + n * kC + c0i);
        const float4 bb = *reinterpret_cast<const float4*>(&bxsh[n * 4]);
        const unsigned kA = (kmsh[c0i * 4 + (n >> 5)] >> (n & 31)) & 1u;
        const unsigned kB = (kmsh[(c0i + 1) * 4 + (n >> 5)] >> (n & 31)) & 1u;
        const float mA = kA ? 1.f : 0.f;
        const float mB = kB ? 1.f : 0.f;
        float* ob = out + (size_t)b * kOutF + (size_t)12 * j;
        float4 q0, q1, q2;
        q0.x = mA * (float)c0i; q0.y = mA * bb.x; q0.z = mA * bb.y; q0.w = mA * bb.z;
        q1.x = mA * bb.w;       q1.y = mA * s2.x; q1.z = mB * (float)(c0i + 1); q1.w = mB * bb.x;
        q2.x = mB * bb.y;       q2.y = mB * bb.z; q2.z = mB * bb.w;             q2.w = mB * s2.y;
        reinterpret_cast<float4*>(ob)[0] = q0;
        reinterpret_cast<float4*>(ob)[1] = q1;
        reinterpret_cast<float4*>(ob)[2] = q2;
    }
}

// ---------------- Fallback: R5 monolithic kernel (known-passing) ----------------
__global__ __launch_bounds__(1024, 8) void yolo_head_mono(const float* __restrict__ x,
                                                          float* __restrict__ out) {
    __shared__ float xs[kS * kS * kFeat];
    __shared__ float scT[kC * kN];
    __shared__ float maxp[kS * kS];
    __shared__ __align__(16) float bxs[kN * 4];
    __shared__ unsigned long long adjLo[kN];
    __shared__ unsigned long long adjHi[kN];
    __shared__ float cscore[16][kN];
    __shared__ unsigned short cidx[16][kN];
    __shared__ unsigned short rnk[16][64];
    __shared__ unsigned short rid[16][64];
    __shared__ unsigned km[kC][4];

    const int b   = blockIdx.x;
    const int tid = threadIdx.x;
    const float* xb = x + (size_t)b * (kS * kS * kFeat);
    if (tid < (kS * kS * kFeat) / 2)
        reinterpret_cast<float2*>(xs)[tid] = reinterpret_cast<const float2*>(xb)[tid];
    __syncthreads();

    if (tid < kS * kS) {
#pragma clang fp contract(off)
        const int cell = tid;
        const float* p = &xs[cell * kFeat];
        float mx = p[0];
        for (int c = 1; c < kC; ++c) mx = fmaxf(mx, p[c]);
        float e[kC];
        float sum = 0.f;
        for (int c = 0; c < kC; ++c) { e[c] = expf(p[c] - mx); sum += e[c]; }
        float conf0 = p[28], conf1 = p[29];
        for (int c = 0; c < kC; ++c) {
            float pr = e[c] / sum;
            scT[c * kN + 2 * cell]     = pr * conf0;
            scT[c * kN + 2 * cell + 1] = pr * conf1;
        }
        maxp[cell] = 1.0f / sum;
    } else if (tid >= 64 && tid < 64 + kN) {
#pragma clang fp contract(off)
        const int n = tid - 64;
        const int cell = n >> 1, k = n & 1;
        const int gi = cell / kS, gj = cell % kS;
        const float* p = &xs[cell * kFeat + kC + 4 * k];
        float cx = (p[0] + (float)gj) / 7.0f;
        float cy = (p[1] + (float)gi) / 7.0f;
        float w = p[2], h = p[3];
        float4 bb;
        bb.x = fminf(fmaxf(cx - w * 0.5f, 0.f), 1.f) * 448.f;
        bb.y = fminf(fmaxf(cy - h * 0.5f, 0.f), 1.f) * 448.f;
        bb.z = fminf(fmaxf(cx + w * 0.5f, 0.f), 1.f) * 448.f;
        bb.w = fminf(fmaxf(cy + h * 0.5f, 0.f), 1.f) * 448.f;
        *reinterpret_cast<float4*>(&bxs[n * 4]) = bb;
    }
    __syncthreads();

    if (tid < 4 * kN) {
        const int i = tid % kN;
        const int w = tid / kN;
        const int cell = i >> 1, k = i & 1;
        if (xs[cell * kFeat + 28 + k] * maxp[cell] >= kScoreT) {
            const float ax1 = bxs[i * 4 + 0], ay1 = bxs[i * 4 + 1];
            const float ax2 = bxs[i * 4 + 2], ay2 = bxs[i * 4 + 3];
            unsigned m = 0;
            const int j0 = 32 * w;
            const int j1 = (j0 + 32 < kN) ? (j0 + 32) : kN;
            for (int j = j0; j < j1; ++j) {
                float v = iou_f(ax1, ay1, ax2, ay2,
                                bxs[j * 4 + 0], bxs[j * 4 + 1],
                                bxs[j * 4 + 2], bxs[j * 4 + 3]);
                if (v > kIouT) m |= (1u << (j - j0));
            }
            if (w < 2) reinterpret_cast<unsigned*>(adjLo)[2 * i + w] = m;
            else       reinterpret_cast<unsigned*>(adjHi)[2 * i + (w - 2)] = m;
        }
    }
    __syncthreads();

    const int wv = tid >> 6;
    const int lane = tid & 63;
    for (int pass = 0; pass < 2; ++pass) {
        const int c = wv + 16 * pass;
        if (c >= kC) break;
        float s0 = scT[c * kN + lane];
        bool c0 = (s0 >= kScoreT);
        float s1 = 0.f;
        bool c1 = false;
        if (lane < kN - 64) {
            s1 = scT[c * kN + 64 + lane];
            c1 = (s1 >= kScoreT);
        }
        const unsigned long long m0 = __ballot(c0);
        const unsigned long long m1 = __ballot(c1);
        const int K0 = __popcll(m0);
        const int K  = K0 + __popcll(m1);
        const unsigned long long lt = (1ull << lane) - 1ull;
        int p0 = 0, p1 = 0;
        if (c0) { p0 = __popcll(m0 & lt); cscore[wv][p0] = s0; cidx[wv][p0] = (unsigned short)lane; }
        if (c1) { p1 = K0 + __popcll(m1 & lt); cscore[wv][p1] = s1; cidx[wv][p1] = (unsigned short)(lane + 64); }
        __builtin_amdgcn_wave_barrier();
        unsigned long long kb0 = 0, kb1 = 0;
        if (K <= 64) {
            const bool act = (lane < K);
            const float sp = act ? cscore[wv][lane] : 0.f;
            int rp = 0;
            for (int q = 0; q < K; ++q) {
                float sq = cscore[wv][q];
                rp += ((sq > sp) || ((sq == sp) && (q < lane))) ? 1 : 0;
            }
            if (act) { rnk[wv][lane] = (unsigned short)rp; rid[wv][rp] = cidx[wv][lane]; }
            __builtin_amdgcn_wave_barrier();
            const int myb = act ? (int)rid[wv][lane] : 0;
            const unsigned long long rLo = adjLo[myb];
            const unsigned long long rHi = adjHi[myb];
            unsigned long long supLo = 0, supHi = 0, keepM = 0;
            for (int r = 0; r < K; ++r) {
                const int bi = __shfl(myb, r);
                const unsigned long long qLo = shfl64(rLo, r);
                const unsigned long long qHi = shfl64(rHi, r);
                const unsigned long long word = (bi & 64) ? supHi : supLo;
                const unsigned long long bit = (word >> (bi & 63)) & 1ull;
                const unsigned long long take = bit - 1ull;
                keepM |= (1ull << r) & take;
                supLo |= qLo & take;
                supHi |= qHi & take;
            }
            const bool k0 = c0 && ((keepM >> rnk[wv][p0]) & 1ull);
            const bool k1 = c1 && ((keepM >> rnk[wv][p1]) & 1ull);
            kb0 = __ballot(k0);
            kb1 = __ballot(k1);
        } else {
            bool al0 = c0, al1 = c1;
            bool k0 = false, k1 = false;
            const float n0x1 = bxs[lane * 4 + 0], n0y1 = bxs[lane * 4 + 1];
            const float n0x2 = bxs[lane * 4 + 2], n0y2 = bxs[lane * 4 + 3];
            float n1x1 = 0.f, n1y1 = 0.f, n1x2 = 0.f, n1y2 = 0.f;
            if (lane < kN - 64) {
                n1x1 = bxs[(lane + 64) * 4 + 0]; n1y1 = bxs[(lane + 64) * 4 + 1];
                n1x2 = bxs[(lane + 64) * 4 + 2]; n1y2 = bxs[(lane + 64) * 4 + 3];
            }
            for (;;) {
                float bs; int bp;
                if (al0 && (!al1 || s0 >= s1)) { bs = s0; bp = p0; }
                else if (al1)                  { bs = s1; bp = p1; }
                else                           { bs = -1e30f; bp = 1 << 20; }
                for (int off = 32; off; off >>= 1) {
                    float os = __shfl_xor(bs, off);
                    int   op = __shfl_xor(bp, off);
                    if (os > bs || (os == bs && op < bp)) { bs = os; bp = op; }
                }
                if (bp >= (1 << 20)) break;
                const int bi = cidx[wv][bp];
                const float4 kbx = *reinterpret_cast<const float4*>(&bxs[bi * 4]);
                if (bp == p0 && al0) { k0 = true; al0 = false; }
                if (bp == p1 && al1) { k1 = true; al1 = false; }
                if (al0 && iou_f(kbx.x, kbx.y, kbx.z, kbx.w, n0x1, n0y1, n0x2, n0y2) > kIouT) al0 = false;
                if (al1 && iou_f(kbx.x, kbx.y, kbx.z, kbx.w, n1x1, n1y1, n1x2, n1y2) > kIouT) al1 = false;
            }
            kb0 = __ballot(k0);
            kb1 = __ballot(k1);
        }
        if (lane == 0) {
            km[c][0] = (unsigned)kb0;
            km[c][1] = (unsigned)(kb0 >> 32);
            km[c][2] = (unsigned)kb1;
            km[c][3] = (unsigned)(kb1 >> 32);
        }
    }
    __syncthreads();

    if (tid < kRows / 2) {
        const int j = tid;
        const int n = j / 10;
        const int c0i = 2 * (j % 10);
        const int c1i = c0i + 1;
        const float4 bb = *reinterpret_cast<const float4*>(&bxs[n * 4]);
        const float sA = scT[c0i * kN + n];
        const float sB = scT[c1i * kN + n];
        const float mA = ((km[c0i][n >> 5] >> (n & 31)) & 1u) ? 1.f : 0.f;
        const float mB = ((km[c1i][n >> 5] >> (n & 31)) & 1u) ? 1.f : 0.f;
        float* ob = out + (size_t)b * kOutF + (size_t)12 * j;
        float4 q0, q1, q2;
        q0.x = mA * (float)c0i; q0.y = mA * bb.x; q0.z = mA * bb.y; q0.w = mA * bb.z;
        q1.x = mA * bb.w;       q1.y = mA * sA;   q1.z = mB * (float)c1i; q1.w = mB * bb.x;
        q2.x = mB * bb.y;       q2.y = mB * bb.z; q2.z = mB * bb.w;       q2.w = mB * sB;
        reinterpret_cast<float4*>(ob)[0] = q0;
        reinterpret_cast<float4*>(ob)[1] = q1;
        reinterpret_cast<float4*>(ob)[2] = q2;
    }
}

extern "C" void kernel_launch(void* const* d_in, const int* in_sizes, int n_in,
                              void* d_out, int out_size, void* d_ws, size_t ws_size,
                              hipStream_t stream) {
    const float* x = (const float*)d_in[0];
    float* out = (float*)d_out;
    const int B = in_sizes[0] / (kS * kS * kFeat);   // 1024

    const size_t szT = (size_t)B * kRows * 4;        // scT [B][20][98]
    const size_t szN = (size_t)B * kRows * 4;        // scN [B][98][20]
    const size_t szB = (size_t)B * kN * 16;          // bxs [B][98][4]
    const size_t szL = (size_t)B * kN * 8;           // adjLo u64
    const size_t szH = (size_t)B * kN * 8;           // adjHi u64
    const size_t szK = (size_t)B * kC * 16;          // km  [B][20][4 u32]
    const size_t need = szT + szN + szB + szL + szH + szK;

    if (ws_size >= need) {
        char* w = (char*)d_ws;
        float* scT = (float*)w;                w += szT;
        float* scN = (float*)w;                w += szN;
        float* bxs = (float*)w;                w += szB;
        unsigned long long* adjLo = (unsigned long long*)w;  w += szL;
        unsigned long long* adjHi = (unsigned long long*)w;  w += szH;
        unsigned* km = (unsigned*)w;

        hipLaunchKernelGGL(yolo_prep_kernel, dim3(B), dim3(256), 0, stream,
                           x, scT, scN, bxs, (unsigned*)adjLo, (unsigned*)adjHi);
        hipLaunchKernelGGL(yolo_nms_kernel, dim3(B * kC / 4), dim3(256), 0, stream,
                           scT, bxs, adjLo, adjHi, km);
        hipLaunchKernelGGL(yolo_write_kernel, dim3(B), dim3(1024), 0, stream,
                           scN, bxs, km, out);
    } else {
        hipLaunchKernelGGL(yolo_head_mono, dim3(B), dim3(1024), 0, stream, x, out);
    }
}

// Round 8
// 85.573 us; speedup vs baseline: 1.4373x; 1.4373x over previous
//
#include <hip/hip_runtime.h>

// YOLOv1 head post-process — R8: monolith (R7 proved the 3-kernel split costs
// +21us: inter-kernel drains + 45MB extra HBM traffic; ws poison-fill is a
// fixed harness cost either way). Attack = delete VALU instructions:
//  * contested-set NMS: candidate overlapping no OTHER candidate is always
//    kept; NMS(cand) = (cand\S) ∪ NMS(S), S = contested set (typ. 0-6 vs
//    K~20). Per class: ~25-inst test, usually no rank/scan at all.
//  * adjacency by wave-ballot: row i = 64-lane IoU + ballot (union-filtered),
//    ~2 rows per wave, replacing the 392-thread x 32-iter loop.
//  * SoA boxes in LDS (stride-4B, conflict-free), hoisted row loads,
//    dynamic class queue (LDS atomicAdd) to balance contested classes.
// Softmax float-op sequence kept bit-identical to R1-R5 (decision safety).
// Equivalence notes (carried, R1-R5 passed):
//  * score < SCORE_T boxes only suppress even-lower-sorted boxes (all zeroed
//    by final score filter) -> NMS over score>=SCORE_T candidates exact.
//  * candidate => conf*(1/sum) >= SCORE_T in float (e[c]<=1, /sum and *conf
//    monotone) -> union-filtered adjacency covers every candidate.
//  * contested restriction exact: non-contested candidates' rows hit no other
//    candidate (IoU symmetric), so they neither suppress nor get suppressed.
//  * rank tie-break = box index ascending = jnp stable argsort(-scores).
//  * K>64 (prob ~0) falls back to ballot-greedy (exact).

namespace {
constexpr int kS    = 7;
constexpr int kC    = 20;
constexpr int kFeat = 30;             // C + 5*BBOX
constexpr int kN    = 98;             // S*S*2 boxes
constexpr int kRows = kN * kC;        // 1960
constexpr int kOutF = kRows * 6;      // 11760 floats per batch
constexpr int kT    = 1024;           // threads per block (16 waves)
constexpr float kIouT   = 0.5f;
constexpr float kScoreT = 0.05f;
}

__device__ __forceinline__ float iou_f(float ax1, float ay1, float ax2, float ay2,
                                       float bx1, float by1, float bx2, float by2) {
#pragma clang fp contract(off)
    float aa = fmaxf(ax2 - ax1, 0.f) * fmaxf(ay2 - ay1, 0.f);
    float ab = fmaxf(bx2 - bx1, 0.f) * fmaxf(by2 - by1, 0.f);
    float ix1 = fmaxf(ax1, bx1);
    float iy1 = fmaxf(ay1, by1);
    float ix2 = fminf(ax2, bx2);
    float iy2 = fminf(ay2, by2);
    float inter = fmaxf(ix2 - ix1, 0.f) * fmaxf(iy2 - iy1, 0.f);
    float uni = aa + ab - inter;
    return inter / fmaxf(uni, 1e-9f);
}

__device__ __forceinline__ unsigned long long shfl64(unsigned long long v, int src) {
    unsigned lo = (unsigned)__shfl((int)(unsigned)(v & 0xffffffffull), src);
    unsigned hi = (unsigned)__shfl((int)(unsigned)(v >> 32), src);
    return ((unsigned long long)hi << 32) | lo;
}

__global__ __launch_bounds__(kT, 8) void yolo_head_kernel(const float* __restrict__ x,
                                                          float* __restrict__ out) {
    __shared__ float xs[kS * kS * kFeat];                   // 1470 input floats
    __shared__ float scT[kRows];                            // scores [c][n]
    __shared__ float maxp[kS * kS];                         // 1/sum per cell
    __shared__ float x1s[kN], y1s[kN], x2s[kN], y2s[kN];    // SoA boxes
    __shared__ unsigned long long adjLo[kN], adjHi[kN];     // IoU>T rows (union only)
    __shared__ float csc[16][kN];                           // per-wave cand scores
    __shared__ unsigned short cid[16][kN];                  // per-wave cand box idx
    __shared__ unsigned short rnk[16][64];                  // S-pos -> rank
    __shared__ unsigned short rid[16][64];                  // rank -> box idx
    __shared__ unsigned km[kC][4];                          // keep mask per class
    __shared__ int ctr;                                     // class queue

    const int b   = blockIdx.x;
    const int tid = threadIdx.x;
    const float* xb = x + (size_t)b * (kS * kS * kFeat);

    if (tid < (kS * kS * kFeat) / 2)
        reinterpret_cast<float2*>(xs)[tid] = reinterpret_cast<const float2*>(xb)[tid];
    if (tid == 0) ctr = 0;
    __syncthreads();

    // ---- phase 1: softmax (wave 0, bit-identical op order) + decode (waves 1-2) ----
    if (tid < kS * kS) {
#pragma clang fp contract(off)
        const int cell = tid;
        const float* p = &xs[cell * kFeat];
        float mx = p[0];
        for (int c = 1; c < kC; ++c) mx = fmaxf(mx, p[c]);
        float e[kC];
        float sum = 0.f;
        for (int c = 0; c < kC; ++c) { e[c] = expf(p[c] - mx); sum += e[c]; }
        const float conf0 = p[28], conf1 = p[29];
        for (int c = 0; c < kC; ++c) {
            float pr = e[c] / sum;
            scT[c * kN + 2 * cell]     = pr * conf0;
            scT[c * kN + 2 * cell + 1] = pr * conf1;
        }
        maxp[cell] = 1.0f / sum;    // exp(0)=1 is the exact max of e[]
    } else if (tid >= 64 && tid < 64 + kN) {
#pragma clang fp contract(off)
        const int n = tid - 64;
        const int cell = n >> 1, k = n & 1;
        const int gi = cell / kS, gj = cell % kS;   // gy=gi, gx=gj
        const float* p = &xs[cell * kFeat + kC + 4 * k];
        float cx = (p[0] + (float)gj) / 7.0f;
        float cy = (p[1] + (float)gi) / 7.0f;
        float w = p[2], h = p[3];
        x1s[n] = fminf(fmaxf(cx - w * 0.5f, 0.f), 1.f) * 448.f;
        y1s[n] = fminf(fmaxf(cy - h * 0.5f, 0.f), 1.f) * 448.f;
        x2s[n] = fminf(fmaxf(cx + w * 0.5f, 0.f), 1.f) * 448.f;
        y2s[n] = fminf(fmaxf(cy + h * 0.5f, 0.f), 1.f) * 448.f;
    }
    __syncthreads();

    const int wv   = tid >> 6;
    const int lane = tid & 63;
    const int nB   = (lane < kN - 64) ? lane + 64 : 0;   // valid dummy for lane>=34

    // ---- phase 2: union mask + ballot-built adjacency (wave wv: rows wv, wv+16, ...) ----
    {
        const float aX1 = x1s[lane], aY1 = y1s[lane], aX2 = x2s[lane], aY2 = y2s[lane];
        const float bX1 = x1s[nB],  bY1 = y1s[nB],  bX2 = x2s[nB],  bY2 = y2s[nB];
        const int cA = lane >> 1, kA = lane & 1;
        const bool uA = xs[cA * kFeat + 28 + kA] * maxp[cA] >= kScoreT;
        bool uB = false;
        if (lane < kN - 64) {
            const int cB = nB >> 1, kB = nB & 1;
            uB = xs[cB * kFeat + 28 + kB] * maxp[cB] >= kScoreT;
        }
        const unsigned long long ULo = __ballot(uA);
        const unsigned long long UHi = __ballot(uB);
        for (int i = wv; i < kN; i += 16) {
            const bool inU = (i < 64) ? ((ULo >> i) & 1ull) : ((UHi >> (i - 64)) & 1ull);
            if (!inU) continue;
            const float iX1 = x1s[i], iY1 = y1s[i], iX2 = x2s[i], iY2 = y2s[i];
            const bool oA = iou_f(iX1, iY1, iX2, iY2, aX1, aY1, aX2, aY2) > kIouT;
            const bool oB = (lane < kN - 64) &&
                            iou_f(iX1, iY1, iX2, iY2, bX1, bY1, bX2, bY2) > kIouT;
            const unsigned long long rLo = __ballot(oA);
            const unsigned long long rHi = __ballot(oB);
            if (lane == 0) { adjLo[i] = rLo; adjHi[i] = rHi; }
        }
    }
    __syncthreads();

    // ---- phase 3: per-class NMS with contested-set restriction, dynamic queue ----
    {
        const unsigned long long rowLoA = adjLo[lane], rowHiA = adjHi[lane];
        const unsigned long long rowLoB = adjLo[nB],   rowHiB = adjHi[nB];
        const unsigned long long selfA  = 1ull << lane;  // A self in Lo; B self in Hi bit `lane`
        const unsigned long long lt     = (1ull << lane) - 1ull;
        for (;;) {
            int c;
            if (lane == 0) c = atomicAdd(&ctr, 1);
            c = __shfl(c, 0);
            if (c >= kC) break;

            const float s0 = scT[c * kN + lane];
            const bool  c0 = (s0 >= kScoreT);
            float s1 = 0.f;
            bool  c1 = false;
            if (lane < kN - 64) { s1 = scT[c * kN + 64 + lane]; c1 = (s1 >= kScoreT); }
            const unsigned long long candLo = __ballot(c0);
            const unsigned long long candHi = __ballot(c1);
            const int K = __popcll(candLo) + __popcll(candHi);

            // contested = candidate overlapping another candidate (rows valid: cand ⊆ union)
            const bool t0 = c0 && ((((rowLoA & candLo) & ~selfA) | (rowHiA & candHi)) != 0ull);
            const bool t1 = c1 && (((rowLoB & candLo) | ((rowHiB & candHi) & ~selfA)) != 0ull);
            const unsigned long long conLo = __ballot(t0);
            const unsigned long long conHi = __ballot(t1);

            unsigned long long keepLo, keepHi;
            if ((conLo | conHi) == 0ull) {
                keepLo = candLo; keepHi = candHi;          // nothing can suppress
            } else if (K <= 64) {
                // rank + scan over the contested set S only (KS <= K <= 64)
                const int KS0 = __popcll(conLo);
                const int KS  = KS0 + __popcll(conHi);
                int q0 = 0, q1 = 0;
                if (t0) { q0 = __popcll(conLo & lt);       csc[wv][q0] = s0; cid[wv][q0] = (unsigned short)lane; }
                if (t1) { q1 = KS0 + __popcll(conHi & lt); csc[wv][q1] = s1; cid[wv][q1] = (unsigned short)(lane + 64); }
                __builtin_amdgcn_wave_barrier();
                const bool  act = (lane < KS);
                const float sp  = act ? csc[wv][lane] : 0.f;
                int rp = 0;
                for (int q = 0; q < KS; ++q) {
                    const float sq = csc[wv][q];           // broadcast read
                    rp += ((sq > sp) || ((sq == sp) && (q < lane))) ? 1 : 0;
                }
                if (act) { rnk[wv][lane] = (unsigned short)rp; rid[wv][rp] = cid[wv][lane]; }
                __builtin_amdgcn_wave_barrier();
                const int myb = act ? (int)rid[wv][lane] : 0;
                const unsigned long long rLo = adjLo[myb];
                const unsigned long long rHi = adjHi[myb];
                unsigned long long supLo = 0, supHi = 0, keepM = 0;
                for (int r = 0; r < KS; ++r) {
                    const int bi = __shfl(myb, r);         // indep of sup chain
                    const unsigned long long qLo = shfl64(rLo, r);
                    const unsigned long long qHi = shfl64(rHi, r);
                    const unsigned long long word = (bi & 64) ? supHi : supLo;
                    const unsigned long long bit  = (word >> (bi & 63)) & 1ull;
                    const unsigned long long take = bit - 1ull;  // ~0 if alive
                    keepM |= (1ull << r) & take;
                    supLo |= qLo & take;
                    supHi |= qHi & take;
                }
                const bool k0 = t0 && ((keepM >> rnk[wv][q0]) & 1ull);
                const bool k1 = t1 && ((keepM >> rnk[wv][q1]) & 1ull);
                keepLo = (candLo & ~conLo) | __ballot(k0);
                keepHi = (candHi & ~conHi) | __ballot(k1);
            } else {
                // fallback (K>64, prob ~0): ballot-greedy over all candidates
                const int K0 = __popcll(candLo);
                int p0 = 0, p1 = 0;
                if (c0) { p0 = __popcll(candLo & lt);      csc[wv][p0] = s0; cid[wv][p0] = (unsigned short)lane; }
                if (c1) { p1 = K0 + __popcll(candHi & lt); csc[wv][p1] = s1; cid[wv][p1] = (unsigned short)(lane + 64); }
                __builtin_amdgcn_wave_barrier();
                bool al0 = c0, al1 = c1, k0 = false, k1 = false;
                const float n0x1 = x1s[lane], n0y1 = y1s[lane], n0x2 = x2s[lane], n0y2 = y2s[lane];
                const float n1x1 = x1s[nB],  n1y1 = y1s[nB],  n1x2 = x2s[nB],  n1y2 = y2s[nB];
                for (;;) {
                    float bs; int bp;
                    if (al0 && (!al1 || s0 >= s1)) { bs = s0; bp = p0; }
                    else if (al1)                  { bs = s1; bp = p1; }
                    else                           { bs = -1e30f; bp = 1 << 20; }
                    for (int off = 32; off; off >>= 1) {
                        const float os = __shfl_xor(bs, off);
                        const int   op = __shfl_xor(bp, off);
                        if (os > bs || (os == bs && op < bp)) { bs = os; bp = op; }
                    }
                    if (bp >= (1 << 20)) break;
                    const int bi = cid[wv][bp];            // wave-uniform
                    const float kx1 = x1s[bi], ky1 = y1s[bi], kx2 = x2s[bi], ky2 = y2s[bi];
                    if (bp == p0 && al0) { k0 = true; al0 = false; }
                    if (bp == p1 && al1) { k1 = true; al1 = false; }
                    if (al0 && iou_f(kx1, ky1, kx2, ky2, n0x1, n0y1, n0x2, n0y2) > kIouT) al0 = false;
                    if (al1 && iou_f(kx1, ky1, kx2, ky2, n1x1, n1y1, n1x2, n1y2) > kIouT) al1 = false;
                }
                keepLo = __ballot(k0);
                keepHi = __ballot(k1);
            }
            if (lane == 0) {
                km[c][0] = (unsigned)keepLo;
                km[c][1] = (unsigned)(keepLo >> 32);
                km[c][2] = (unsigned)keepHi;
                km[c][3] = (unsigned)(keepHi >> 32);
            }
        }
    }
    __syncthreads();

    // ---- phase 4: writer — thread j emits rows 2j,2j+1 (same n) as 3 float4 ----
    if (tid < kRows / 2) {
        const int j = tid;
        const int n = j / 10;                 // rows 2j,2j+1 share n
        const int c0i = 2 * (j % 10);
        const int c1i = c0i + 1;
        const float sA = scT[c0i * kN + n];
        const float sB = scT[c1i * kN + n];
        const float bbx = x1s[n], bby = y1s[n], bbz = x2s[n], bbw = y2s[n];
        const float mA = ((km[c0i][n >> 5] >> (n & 31)) & 1u) ? 1.f : 0.f;
        const float mB = ((km[c1i][n >> 5] >> (n & 31)) & 1u) ? 1.f : 0.f;
        float* ob = out + (size_t)b * kOutF + (size_t)12 * j;
        float4 q0, q1, q2;
        q0.x = mA * (float)c0i; q0.y = mA * bbx; q0.z = mA * bby; q0.w = mA * bbz;
        q1.x = mA * bbw;        q1.y = mA * sA;  q1.z = mB * (float)c1i; q1.w = mB * bbx;
        q2.x = mB * bby;        q2.y = mB * bbz; q2.z = mB * bbw;        q2.w = mB * sB;
        reinterpret_cast<float4*>(ob)[0] = q0;
        reinterpret_cast<float4*>(ob)[1] = q1;
        reinterpret_cast<float4*>(ob)[2] = q2;
    }
}

extern "C" void kernel_launch(void* const* d_in, const int* in_sizes, int n_in,
                              void* d_out, int out_size, void* d_ws, size_t ws_size,
                              hipStream_t stream) {
    const float* x = (const float*)d_in[0];
    float* out = (float*)d_out;
    const int B = in_sizes[0] / (kS * kS * kFeat);   // 1024
    hipLaunchKernelGGL(yolo_head_kernel, dim3(B), dim3(kT), 0, stream, x, out);
}

// Round 9
// 83.640 us; speedup vs baseline: 1.4705x; 1.0231x over previous
//
#include <hip/hip_runtime.h>

// YOLOv1 head post-process — R9: R8's contested-set monolith (46->~30us) at
// 256 threads/block. R8 ran 1024-thr blocks: 2 resident blocks/CU, 2 rounds,
// so the barriered phase chain (load->softmax->adj->NMS->write) had almost
// nothing to overlap with => latency-bound ~3x above the ~11us issue+store
// floor. 256-thr blocks: 4 blocks/CU, all 1024 co-resident, barriers sync 4
// waves, 4 independent chains interleave per CU. Work per batch unchanged:
//  * contested-set NMS: candidate overlapping no OTHER candidate is always
//    kept; NMS(cand) = (cand\S) ∪ NMS(S). Per class usually no rank/scan.
//  * adjacency by wave-ballot, union-filtered (~30 rows not 98).
//  * SoA boxes in LDS; static class map c = wv + 4*pass (atomic queue dropped:
//    5 classes/wave, queue latency > imbalance saved).
// Softmax float-op sequence bit-identical to R1-R8 (decision safety).
// Equivalence notes (carried, R1-R5/R8 passed):
//  * score < SCORE_T boxes only suppress even-lower-sorted boxes (all zeroed
//    by final score filter) -> NMS over score>=SCORE_T candidates exact.
//  * candidate => conf*(1/sum) >= SCORE_T in float (monotone) -> union mask
//    covers every possible candidate.
//  * contested restriction exact (IoU symmetric).
//  * rank tie-break = box index ascending = jnp stable argsort(-scores).
//  * K>64 (prob ~0) falls back to ballot-greedy (exact).

namespace {
constexpr int kS    = 7;
constexpr int kC    = 20;
constexpr int kFeat = 30;             // C + 5*BBOX
constexpr int kN    = 98;             // S*S*2 boxes
constexpr int kRows = kN * kC;        // 1960
constexpr int kOutF = kRows * 6;      // 11760 floats per batch
constexpr int kT    = 256;            // threads per block (4 waves)
constexpr float kIouT   = 0.5f;
constexpr float kScoreT = 0.05f;
}

__device__ __forceinline__ float iou_f(float ax1, float ay1, float ax2, float ay2,
                                       float bx1, float by1, float bx2, float by2) {
#pragma clang fp contract(off)
    float aa = fmaxf(ax2 - ax1, 0.f) * fmaxf(ay2 - ay1, 0.f);
    float ab = fmaxf(bx2 - bx1, 0.f) * fmaxf(by2 - by1, 0.f);
    float ix1 = fmaxf(ax1, bx1);
    float iy1 = fmaxf(ay1, by1);
    float ix2 = fminf(ax2, bx2);
    float iy2 = fminf(ay2, by2);
    float inter = fmaxf(ix2 - ix1, 0.f) * fmaxf(iy2 - iy1, 0.f);
    float uni = aa + ab - inter;
    return inter / fmaxf(uni, 1e-9f);
}

__device__ __forceinline__ unsigned long long shfl64(unsigned long long v, int src) {
    unsigned lo = (unsigned)__shfl((int)(unsigned)(v & 0xffffffffull), src);
    unsigned hi = (unsigned)__shfl((int)(unsigned)(v >> 32), src);
    return ((unsigned long long)hi << 32) | lo;
}

__global__ __launch_bounds__(kT, 4) void yolo_head_kernel(const float* __restrict__ x,
                                                          float* __restrict__ out) {
    __shared__ float xs[kS * kS * kFeat];                   // 1470 input floats
    __shared__ float scT[kRows];                            // scores [c][n]
    __shared__ float maxp[kS * kS];                         // 1/sum per cell
    __shared__ float x1s[kN], y1s[kN], x2s[kN], y2s[kN];    // SoA boxes
    __shared__ unsigned long long adjLo[kN], adjHi[kN];     // IoU>T rows (union only)
    __shared__ float csc[4][kN];                            // per-wave cand scores
    __shared__ unsigned short cid[4][kN];                   // per-wave cand box idx
    __shared__ unsigned short rnk[4][64];                   // S-pos -> rank
    __shared__ unsigned short rid[4][64];                   // rank -> box idx
    __shared__ unsigned km[kC][4];                          // keep mask per class

    const int b   = blockIdx.x;
    const int tid = threadIdx.x;
    const float* xb = x + (size_t)b * (kS * kS * kFeat);

    for (int e = tid; e < (kS * kS * kFeat) / 2; e += kT)
        reinterpret_cast<float2*>(xs)[e] = reinterpret_cast<const float2*>(xb)[e];
    __syncthreads();

    // ---- phase 1: softmax (threads 0-48, bit-identical op order) + decode (64-161) ----
    if (tid < kS * kS) {
#pragma clang fp contract(off)
        const int cell = tid;
        const float* p = &xs[cell * kFeat];
        float mx = p[0];
        for (int c = 1; c < kC; ++c) mx = fmaxf(mx, p[c]);
        float e[kC];
        float sum = 0.f;
        for (int c = 0; c < kC; ++c) { e[c] = expf(p[c] - mx); sum += e[c]; }
        const float conf0 = p[28], conf1 = p[29];
        for (int c = 0; c < kC; ++c) {
            float pr = e[c] / sum;
            scT[c * kN + 2 * cell]     = pr * conf0;
            scT[c * kN + 2 * cell + 1] = pr * conf1;
        }
        maxp[cell] = 1.0f / sum;    // exp(0)=1 is the exact max of e[]
    } else if (tid >= 64 && tid < 64 + kN) {
#pragma clang fp contract(off)
        const int n = tid - 64;
        const int cell = n >> 1, k = n & 1;
        const int gi = cell / kS, gj = cell % kS;   // gy=gi, gx=gj
        const float* p = &xs[cell * kFeat + kC + 4 * k];
        float cx = (p[0] + (float)gj) / 7.0f;
        float cy = (p[1] + (float)gi) / 7.0f;
        float w = p[2], h = p[3];
        x1s[n] = fminf(fmaxf(cx - w * 0.5f, 0.f), 1.f) * 448.f;
        y1s[n] = fminf(fmaxf(cy - h * 0.5f, 0.f), 1.f) * 448.f;
        x2s[n] = fminf(fmaxf(cx + w * 0.5f, 0.f), 1.f) * 448.f;
        y2s[n] = fminf(fmaxf(cy + h * 0.5f, 0.f), 1.f) * 448.f;
    }
    __syncthreads();

    const int wv   = tid >> 6;
    const int lane = tid & 63;
    const int nB   = (lane < kN - 64) ? lane + 64 : 0;   // valid dummy for lane>=34

    // ---- phase 2: union mask + ballot-built adjacency (wave wv: rows wv, wv+4, ...) ----
    {
        const float aX1 = x1s[lane], aY1 = y1s[lane], aX2 = x2s[lane], aY2 = y2s[lane];
        const float bX1 = x1s[nB],  bY1 = y1s[nB],  bX2 = x2s[nB],  bY2 = y2s[nB];
        const int cA = lane >> 1, kA = lane & 1;
        const bool uA = xs[cA * kFeat + 28 + kA] * maxp[cA] >= kScoreT;
        bool uB = false;
        if (lane < kN - 64) {
            const int cB = nB >> 1, kB = nB & 1;
            uB = xs[cB * kFeat + 28 + kB] * maxp[cB] >= kScoreT;
        }
        const unsigned long long ULo = __ballot(uA);
        const unsigned long long UHi = __ballot(uB);
        for (int i = wv; i < kN; i += 4) {
            const bool inU = (i < 64) ? ((ULo >> i) & 1ull) : ((UHi >> (i - 64)) & 1ull);
            if (!inU) continue;
            const float iX1 = x1s[i], iY1 = y1s[i], iX2 = x2s[i], iY2 = y2s[i];
            const bool oA = iou_f(iX1, iY1, iX2, iY2, aX1, aY1, aX2, aY2) > kIouT;
            const bool oB = (lane < kN - 64) &&
                            iou_f(iX1, iY1, iX2, iY2, bX1, bY1, bX2, bY2) > kIouT;
            const unsigned long long rLo = __ballot(oA);
            const unsigned long long rHi = __ballot(oB);
            if (lane == 0) { adjLo[i] = rLo; adjHi[i] = rHi; }
        }
    }
    __syncthreads();

    // ---- phase 3: per-class NMS with contested-set restriction (static 5/wave) ----
    {
        const unsigned long long rowLoA = adjLo[lane], rowHiA = adjHi[lane];
        const unsigned long long rowLoB = adjLo[nB],   rowHiB = adjHi[nB];
        const unsigned long long selfA  = 1ull << lane;  // A self in Lo; B self in Hi bit `lane`
        const unsigned long long lt     = (1ull << lane) - 1ull;
        for (int pass = 0; pass < 5; ++pass) {
            const int c = wv + 4 * pass;                 // always < 20

            const float s0 = scT[c * kN + lane];
            const bool  c0 = (s0 >= kScoreT);
            float s1 = 0.f;
            bool  c1 = false;
            if (lane < kN - 64) { s1 = scT[c * kN + 64 + lane]; c1 = (s1 >= kScoreT); }
            const unsigned long long candLo = __ballot(c0);
            const unsigned long long candHi = __ballot(c1);
            const int K = __popcll(candLo) + __popcll(candHi);

            // contested = candidate overlapping another candidate (rows valid: cand ⊆ union)
            const bool t0 = c0 && ((((rowLoA & candLo) & ~selfA) | (rowHiA & candHi)) != 0ull);
            const bool t1 = c1 && (((rowLoB & candLo) | ((rowHiB & candHi) & ~selfA)) != 0ull);
            const unsigned long long conLo = __ballot(t0);
            const unsigned long long conHi = __ballot(t1);

            unsigned long long keepLo, keepHi;
            if ((conLo | conHi) == 0ull) {
                keepLo = candLo; keepHi = candHi;          // nothing can suppress
            } else if (K <= 64) {
                // rank + scan over the contested set S only (KS <= K <= 64)
                const int KS0 = __popcll(conLo);
                const int KS  = KS0 + __popcll(conHi);
                int q0 = 0, q1 = 0;
                if (t0) { q0 = __popcll(conLo & lt);       csc[wv][q0] = s0; cid[wv][q0] = (unsigned short)lane; }
                if (t1) { q1 = KS0 + __popcll(conHi & lt); csc[wv][q1] = s1; cid[wv][q1] = (unsigned short)(lane + 64); }
                __builtin_amdgcn_wave_barrier();
                const bool  act = (lane < KS);
                const float sp  = act ? csc[wv][lane] : 0.f;
                int rp = 0;
                for (int q = 0; q < KS; ++q) {
                    const float sq = csc[wv][q];           // broadcast read
                    rp += ((sq > sp) || ((sq == sp) && (q < lane))) ? 1 : 0;
                }
                if (act) { rnk[wv][lane] = (unsigned short)rp; rid[wv][rp] = cid[wv][lane]; }
                __builtin_amdgcn_wave_barrier();
                const int myb = act ? (int)rid[wv][lane] : 0;
                const unsigned long long rLo = adjLo[myb];
                const unsigned long long rHi = adjHi[myb];
                unsigned long long supLo = 0, supHi = 0, keepM = 0;
                for (int r = 0; r < KS; ++r) {
                    const int bi = __shfl(myb, r);         // indep of sup chain
                    const unsigned long long qLo = shfl64(rLo, r);
                    const unsigned long long qHi = shfl64(rHi, r);
                    const unsigned long long word = (bi & 64) ? supHi : supLo;
                    const unsigned long long bit  = (word >> (bi & 63)) & 1ull;
                    const unsigned long long take = bit - 1ull;  // ~0 if alive
                    keepM |= (1ull << r) & take;
                    supLo |= qLo & take;
                    supHi |= qHi & take;
                }
                const bool k0 = t0 && ((keepM >> rnk[wv][q0]) & 1ull);
                const bool k1 = t1 && ((keepM >> rnk[wv][q1]) & 1ull);
                keepLo = (candLo & ~conLo) | __ballot(k0);
                keepHi = (candHi & ~conHi) | __ballot(k1);
            } else {
                // fallback (K>64, prob ~0): ballot-greedy over all candidates
                const int K0 = __popcll(candLo);
                int p0 = 0, p1 = 0;
                if (c0) { p0 = __popcll(candLo & lt);      csc[wv][p0] = s0; cid[wv][p0] = (unsigned short)lane; }
                if (c1) { p1 = K0 + __popcll(candHi & lt); csc[wv][p1] = s1; cid[wv][p1] = (unsigned short)(lane + 64); }
                __builtin_amdgcn_wave_barrier();
                bool al0 = c0, al1 = c1, k0 = false, k1 = false;
                const float n0x1 = x1s[lane], n0y1 = y1s[lane], n0x2 = x2s[lane], n0y2 = y2s[lane];
                const float n1x1 = x1s[nB],  n1y1 = y1s[nB],  n1x2 = x2s[nB],  n1y2 = y2s[nB];
                for (;;) {
                    float bs; int bp;
                    if (al0 && (!al1 || s0 >= s1)) { bs = s0; bp = p0; }
                    else if (al1)                  { bs = s1; bp = p1; }
                    else                           { bs = -1e30f; bp = 1 << 20; }
                    for (int off = 32; off; off >>= 1) {
                        const float os = __shfl_xor(bs, off);
                        const int   op = __shfl_xor(bp, off);
                        if (os > bs || (os == bs && op < bp)) { bs = os; bp = op; }
                    }
                    if (bp >= (1 << 20)) break;
                    const int bi = cid[wv][bp];            // wave-uniform
                    const float kx1 = x1s[bi], ky1 = y1s[bi], kx2 = x2s[bi], ky2 = y2s[bi];
                    if (bp == p0 && al0) { k0 = true; al0 = false; }
                    if (bp == p1 && al1) { k1 = true; al1 = false; }
                    if (al0 && iou_f(kx1, ky1, kx2, ky2, n0x1, n0y1, n0x2, n0y2) > kIouT) al0 = false;
                    if (al1 && iou_f(kx1, ky1, kx2, ky2, n1x1, n1y1, n1x2, n1y2) > kIouT) al1 = false;
                }
                keepLo = __ballot(k0);
                keepHi = __ballot(k1);
            }
            if (lane == 0) {
                km[c][0] = (unsigned)keepLo;
                km[c][1] = (unsigned)(keepLo >> 32);
                km[c][2] = (unsigned)keepHi;
                km[c][3] = (unsigned)(keepHi >> 32);
            }
        }
    }
    __syncthreads();

    // ---- phase 4: writer — thread j emits rows 2j,2j+1 (same n) as 3 float4 ----
    for (int j = tid; j < kRows / 2; j += kT) {
        const int n = j / 10;                 // rows 2j,2j+1 share n
        const int c0i = 2 * (j % 10);
        const int c1i = c0i + 1;
        const float sA = scT[c0i * kN + n];
        const float sB = scT[c1i * kN + n];
        const float bbx = x1s[n], bby = y1s[n], bbz = x2s[n], bbw = y2s[n];
        const float mA = ((km[c0i][n >> 5] >> (n & 31)) & 1u) ? 1.f : 0.f;
        const float mB = ((km[c1i][n >> 5] >> (n & 31)) & 1u) ? 1.f : 0.f;
        float* ob = out + (size_t)b * kOutF + (size_t)12 * j;
        float4 q0, q1, q2;
        q0.x = mA * (float)c0i; q0.y = mA * bbx; q0.z = mA * bby; q0.w = mA * bbz;
        q1.x = mA * bbw;        q1.y = mA * sA;  q1.z = mB * (float)c1i; q1.w = mB * bbx;
        q2.x = mB * bby;        q2.y = mB * bbz; q2.z = mB * bbw;        q2.w = mB * sB;
        reinterpret_cast<float4*>(ob)[0] = q0;
        reinterpret_cast<float4*>(ob)[1] = q1;
        reinterpret_cast<float4*>(ob)[2] = q2;
    }
}

extern "C" void kernel_launch(void* const* d_in, const int* in_sizes, int n_in,
                              void* d_out, int out_size, void* d_ws, size_t ws_size,
                              hipStream_t stream) {
    const float* x = (const float*)d_in[0];
    float* out = (float*)d_out;
    const int B = in_sizes[0] / (kS * kS * kFeat);   // 1024
    hipLaunchKernelGGL(yolo_head_kernel, dim3(B), dim3(kT), 0, stream, x, out);
}